// Round 10
// baseline (376.935 us; speedup 1.0000x reference)
//
#include <hip/hip_runtime.h>
#include <hip/hip_fp16.h>
#include <stdint.h>

#define BB 16
#define NN 1620
#define DD 64
#define CC 128
#define KK 32
#define EPSV 1e-5f
#define PAIRS (BB*NN)            // 25920
#define ROWS  (PAIRS*KK)         // 829440
#define TILES (PAIRS/2)          // 12960 tiles of 64 rows
#define TPB_TILES 8
#define GRID_MM (TILES/TPB_TILES) // 1620
#define NCHUNK 26                // ceil(1620/64)
#define GRAM_BLOCKS 256
#define MSTRIDE 12416            // 3*4096 mats + 64 vcf + 64 vf
#define QPB 4                    // knn queries per 256-thread block
#define HSTRIDE 264              // replica stride (ints): 264 % 32 == 8 ->
                                 // replicas of a bin land in 4 DISTINCT banks

typedef _Float16 half8 __attribute__((ext_vector_type(8)));
typedef float f32x4 __attribute__((ext_vector_type(4)));

__device__ __forceinline__ float relu_(float v){ return v > 0.f ? v : 0.f; }

union H2U { __half2 h; unsigned u; };

// ---------------- fused prologue: transpose x -> feats fp16, convert w,
// zero cnt/stats (absorbs k_convert_w + both memsets; 416 blocks x 256) ----
__global__ void __launch_bounds__(256) k_prep_feats(const float* __restrict__ x,
                                                    __half* __restrict__ feats,
                                                    const float* __restrict__ w1,
                                                    const float* __restrict__ w2,
                                                    __half* __restrict__ w1h,
                                                    __half* __restrict__ w2h,
                                                    int* __restrict__ cnt,
                                                    float* __restrict__ stats) {
    __shared__ float t[64*65];
    int b = blockIdx.y;
    int n0 = blockIdx.x * 64;
    int tid = threadIdx.x;

    // distributed side-work: w convert (16384) + cnt zero (25920) + stats zero (512)
    {
        int gid = (blockIdx.y * gridDim.x + blockIdx.x)*256 + tid;
        if (gid < CC*CC) {
            w1h[gid] = __float2half(w1[gid]);
            w2h[gid] = __float2half(w2[gid]);
        }
        int zid = gid - CC*CC;
        if (zid >= 0 && zid < PAIRS) cnt[zid] = 0;
        int sid = zid - PAIRS;
        if (sid >= 0 && sid < 512) stats[sid] = 0.f;
    }

#pragma unroll
    for (int i = 0; i < 16; ++i) {
        int idx = i*256 + tid;
        int d = idx >> 6, nl = idx & 63;
        int n = n0 + nl;
        float v = 0.f;
        if (n < NN) v = x[((size_t)b*DD + d)*NN + n];
        t[d*65 + nl] = v;
    }
    __syncthreads();
#pragma unroll
    for (int i = 0; i < 8; ++i) {
        int idx = i*256 + tid;            // 64 nl x 32 d-pairs
        int nl = idx >> 5, dp = idx & 31;
        int n = n0 + nl;
        if (n < NN) {
            __half2 h = __floats2half2_rn(t[(dp*2)*65 + nl], t[(dp*2+1)*65 + nl]);
            *(__half2*)(feats + ((size_t)b*NN + n)*DD + dp*2) = h;
        }
    }
}

// ---------------- KNN: radix-histogram rank selection ----------------
// Locked (rounds 6-9): QPB=4 waves/block, block-staged SoA coords in LDS,
// HSTRIDE=264 bank-true 4-way replicated histograms.
__global__ void __launch_bounds__(256) k_knn(const float* __restrict__ coords,
                                             int* __restrict__ idx_out,
                                             int* __restrict__ cnt) {
#pragma clang fp contract(off)
    __shared__ int hist[QPB][4*HSTRIDE];  // 16.9 KB
    __shared__ unsigned bcast[QPB][2];
    __shared__ float cxs[NN], cys[NN], czs[NN];   // 19.4 KB SoA coords
    int tid = threadIdx.x;
    int w = tid >> 6, lane = tid & 63;
    int p = blockIdx.x*QPB + w;
    int b = (blockIdx.x*QPB) / NN;        // block-uniform (NN % QPB == 0)
    int n = p - b*NN;
    const float* cb = coords + (size_t)b*NN*3;

    // stage coords (block-wide, 12B/thread contiguous) + zero histograms
    for (int i = tid; i < NN; i += 256) {
        float3 c = *(const float3*)(cb + i*3);
        cxs[i] = c.x; cys[i] = c.y; czs[i] = c.z;
    }
    for (int i = lane; i < 4*HSTRIDE; i += 64) hist[w][i] = 0;
    __syncthreads();

    float qx = cxs[n], qy = cys[n], qz = czs[n];
    float sqn = (qx*qx + qy*qy) + qz*qz;

    unsigned key[NCHUNK];
#pragma unroll
    for (int i = 0; i < NCHUNK; ++i) {
        int m = lane + i*64;
        unsigned u = 0xFFFFFFFFu;
        if (m < NN) {
            float cx = cxs[m], cy = cys[m], cz = czs[m];
            float sqm = (cx*cx + cy*cy) + cz*cz;
            float dot = (qx*cx + qy*cy) + qz*cz;
            float d = (sqn + sqm) - 2.0f*dot;
            unsigned t = __float_as_uint(d);
            u = (t & 0x80000000u) ? ~t : (t | 0x80000000u);
        }
        key[i] = u;
    }
    int* hrep = hist[w] + (lane & 3)*HSTRIDE;

    // ---- pass A: histogram on key[31:24] ----
#pragma unroll
    for (int i = 0; i < NCHUNK; ++i) {
        int m = lane + i*64;
        if (m < NN) atomicAdd(&hrep[key[i] >> 24], 1);
    }
    __syncthreads();
    {
        int v0 = 0, v1 = 0, v2 = 0, v3 = 0;
#pragma unroll
        for (int c = 0; c < 4; ++c) {
            const int* h = hist[w] + c*HSTRIDE;
            v0 += h[lane*4+0]; v1 += h[lane*4+1];
            v2 += h[lane*4+2]; v3 += h[lane*4+3];
        }
        int c1 = v0+v1, c2 = c1+v2, c3 = c2+v3;
        int inc = c3;
#pragma unroll
        for (int off = 1; off < 64; off <<= 1) {
            int t = __shfl_up(inc, off);
            if (lane >= off) inc += t;
        }
        int base = inc - c3;
        if (base < KK) {
            int u0 = base+v0, u1 = base+c1, u2 = base+c2, u3 = base+c3;
            if      (u0 >= KK) { bcast[w][0] = lane*4+0; bcast[w][1] = base; }
            else if (u1 >= KK) { bcast[w][0] = lane*4+1; bcast[w][1] = u0; }
            else if (u2 >= KK) { bcast[w][0] = lane*4+2; bcast[w][1] = u1; }
            else if (u3 >= KK) { bcast[w][0] = lane*4+3; bcast[w][1] = u2; }
        }
    }
    __syncthreads();
    unsigned BA = bcast[w][0];
    int rA = KK - (int)bcast[w][1];
    __syncthreads();

    // ---- pass B: histogram on key[23:16] within bucket BA ----
    for (int i = lane; i < 4*HSTRIDE; i += 64) hist[w][i] = 0;
    __syncthreads();
#pragma unroll
    for (int i = 0; i < NCHUNK; ++i) {
        int m = lane + i*64;
        if (m < NN && (key[i] >> 24) == BA) atomicAdd(&hrep[(key[i] >> 16) & 255], 1);
    }
    __syncthreads();
    {
        int v0 = 0, v1 = 0, v2 = 0, v3 = 0;
#pragma unroll
        for (int c = 0; c < 4; ++c) {
            const int* h = hist[w] + c*HSTRIDE;
            v0 += h[lane*4+0]; v1 += h[lane*4+1];
            v2 += h[lane*4+2]; v3 += h[lane*4+3];
        }
        int c1 = v0+v1, c2 = c1+v2, c3 = c2+v3;
        int inc = c3;
#pragma unroll
        for (int off = 1; off < 64; off <<= 1) {
            int t = __shfl_up(inc, off);
            if (lane >= off) inc += t;
        }
        int base = inc - c3;
        if (base < rA) {
            int u0 = base+v0, u1 = base+c1, u2 = base+c2, u3 = base+c3;
            if      (u0 >= rA) { bcast[w][0] = lane*4+0; bcast[w][1] = base; }
            else if (u1 >= rA) { bcast[w][0] = lane*4+1; bcast[w][1] = u0; }
            else if (u2 >= rA) { bcast[w][0] = lane*4+2; bcast[w][1] = u1; }
            else if (u3 >= rA) { bcast[w][0] = lane*4+3; bcast[w][1] = u2; }
        }
    }
    __syncthreads();
    unsigned prefix16 = (BA << 8) | bcast[w][0];
    int r = rA - (int)bcast[w][1];

    // ---- extract exact 32nd (key, m) pair (wave-local, no barriers) ----
    unsigned long long fl = 0;
    for (int round = 0; round < r; ++round) {
        unsigned long long best = ~0ull;
#pragma unroll
        for (int i = 0; i < NCHUNK; ++i) {
            if ((key[i] >> 16) == prefix16) {
                unsigned long long v = ((unsigned long long)key[i] << 32) | (unsigned)(lane + i*64);
                if (v > fl && v < best) best = v;
            }
        }
#pragma unroll
        for (int off = 32; off; off >>= 1) {
            unsigned long long o = __shfl_xor(best, off, 64);
            if (o < best) best = o;
        }
        fl = best;
    }
    unsigned kstar = (unsigned)(fl >> 32);
    unsigned mstar = (unsigned)fl;

    int cnt_ = 0;
    unsigned long long mylow = (1ull << lane) - 1ull;
#pragma unroll
    for (int i = 0; i < NCHUNK; ++i) {
        unsigned m = lane + i*64;
        bool sel = (key[i] < kstar) || (key[i] == kstar && m <= mstar);
        unsigned long long bal = __ballot(sel);
        if (sel) {
            int pos = cnt_ + __popcll(bal & mylow);
            idx_out[p*KK + pos] = (int)m;
            atomicAdd(&cnt[b*NN + (int)m], 1);
        }
        cnt_ += __popcll(bal);
    }
}

// ---------------- gram (absorbs gather-sum): per-block partial M1/M2/M3 ----
// s_p = sum_k feats[nb(p,k)] computed inline during staging (32 coalesced
// gathered rows per pair, feats is L2-resident) -- kills the s_arr
// round-trip and the separate k_gather_sum dispatch.
__global__ void __launch_bounds__(256) k_gram(const __half* __restrict__ feats,
                                              const int* __restrict__ knn_idx,
                                              const int* __restrict__ cnt,
                                              float* __restrict__ Mpart) {
    __shared__ float fs[4][64];
    __shared__ float ss[4][64];
    __shared__ float cs[4];
    int tid = threadIdx.x;
    int rt = tid >> 4, ct = tid & 15;
    int r0 = rt*4, c0 = ct*4;
    float m1a[4][4] = {{0}}, m2a[4][4] = {{0}}, m3a[4][4] = {{0}};
    float vcf4[4] = {0,0,0,0}, vf4[4] = {0,0,0,0};

    int per = (PAIRS + GRAM_BLOCKS - 1)/GRAM_BLOCKS;   // 102 (wait: 25920/256=101.25 -> 102)
    int p0 = blockIdx.x * per;
    int p1 = p0 + per; if (p1 > PAIRS) p1 = PAIRS;

    for (int pc = p0; pc < p1; pc += 4) {
        __syncthreads();
        int sub = tid >> 6, l = tid & 63;
        int pp = pc + sub;
        if (pp < p1) {
            int bbase = (pp / NN) * NN;
            fs[sub][l] = __half2float(feats[(size_t)pp*DD + l]);
            int idx = 0;
            if (l < KK) idx = knn_idx[pp*KK + l];
            float s = 0.f;
#pragma unroll
            for (int k = 0; k < KK; ++k) {
                int nb = __shfl(idx, k);
                s += __half2float(feats[((size_t)(bbase + nb))*DD + l]);
            }
            ss[sub][l] = s;
            if (l == 0) cs[sub] = (float)cnt[pp];
        }
        __syncthreads();
        int e = p1 - pc; if (e > 4) e = 4;
        for (int j = 0; j < e; ++j) {
            float cn = cs[j];
            float fr[4], sr[4], fc[4];
#pragma unroll
            for (int a = 0; a < 4; ++a) { fr[a] = fs[j][r0+a]; sr[a] = ss[j][r0+a]; fc[a] = fs[j][c0+a]; }
#pragma unroll
            for (int a = 0; a < 4; ++a) {
                float cfr = cn * fr[a];
#pragma unroll
                for (int bc = 0; bc < 4; ++bc) {
                    m1a[a][bc] = fmaf(cfr,   fc[bc], m1a[a][bc]);
                    m2a[a][bc] = fmaf(sr[a], fc[bc], m2a[a][bc]);
                    m3a[a][bc] = fmaf(fr[a], fc[bc], m3a[a][bc]);
                }
                if (ct == 0) { vcf4[a] += cfr; vf4[a] += fr[a]; }
            }
        }
    }
    float* out = Mpart + (size_t)blockIdx.x * MSTRIDE;
#pragma unroll
    for (int a = 0; a < 4; ++a)
#pragma unroll
        for (int bc = 0; bc < 4; ++bc) {
            int idx = (r0+a)*64 + c0+bc;
            out[idx]        = m1a[a][bc];
            out[4096 + idx] = m2a[a][bc];
            out[8192 + idx] = m3a[a][bc];
        }
    if (ct == 0)
#pragma unroll
        for (int a = 0; a < 4; ++a) {
            out[12288 + r0+a] = vcf4[a];
            out[12352 + r0+a] = vf4[a];
        }
}

__global__ void __launch_bounds__(256) k_gram_reduce(const float* __restrict__ Mpart,
                                                     float* __restrict__ Mfin) {
    int e = blockIdx.x*256 + threadIdx.x;
    if (e < MSTRIDE) {
        float s = 0.f;
        for (int p = 0; p < GRAM_BLOCKS; ++p) s += Mpart[(size_t)p*MSTRIDE + e];
        Mfin[e] = s;
    }
}

// ---------------- stats1 from Gram: one block per output channel o ----------------
__global__ void __launch_bounds__(256) k_stats1(const float* __restrict__ M,
                                                const __half* __restrict__ w1h,
                                                const float* __restrict__ g1,
                                                const float* __restrict__ b1,
                                                float* __restrict__ ab1) {
    __shared__ float wl[64], wr[64];
    __shared__ float redA[256], redB[256];
    int o = blockIdx.x, tid = threadIdx.x;
    if (tid < 64)       wl[tid]    = __half2float(w1h[o*CC + tid]);
    else if (tid < 128) wr[tid-64] = __half2float(w1h[o*CC + tid]);
    __syncthreads();
    const float* M1 = M;
    const float* M2 = M + 4096;
    const float* M3 = M + 8192;
    const float* vcf = M + 12288;
    const float* vf  = M + 12352;
    float part = 0.f;
    for (int e = tid; e < 4096; e += 256) {
        int i = e >> 6, j = e & 63;
        float m1 = M1[e], m2 = M2[e], m2t = M2[j*64 + i], m3 = M3[e];
        float A  = m1 - m2 - m2t + 32.f*m3;   // sum u u^T
        float Bc = m2 - 32.f*m3;              // sum u v^T
        part += wl[i]*(A*wl[j] + 2.f*Bc*wr[j]) + 32.f*wr[i]*m3*wr[j];
    }
    float psum = 0.f;
    if (tid < 64) psum = wl[tid]*(vcf[tid] - 32.f*vf[tid]) + 32.f*wr[tid]*vf[tid];
    redA[tid] = part; redB[tid] = psum;
    __syncthreads();
    for (int s = 128; s > 0; s >>= 1) {
        if (tid < s) { redA[tid] += redA[tid+s]; redB[tid] += redB[tid+s]; }
        __syncthreads();
    }
    if (tid == 0) {
        float sumsq = redA[0], sum = redB[0];
        float mean = sum / (float)ROWS;
        float var  = sumsq / (float)ROWS - mean*mean;
        float a = g1[o] * rsqrtf(var + EPSV);
        ab1[o] = a;
        ab1[CC + o] = b1[o] - mean*a;
    }
}

// ============ staging helpers: coalesced gather + XOR-swizzled LDS ============
__device__ __forceinline__ void fill_bases(const int* __restrict__ knn_idx,
                                           int blk, int tid, int* rowb) {
#pragma unroll
    for (int e = tid; e < TPB_TILES*64; e += 256) {
        int tile = blk*TPB_TILES + (e >> 6);
        int rr = e & 63;
        int p = tile*2 + (rr >> 5);
        int nb = knn_idx[p*KK + (rr & 31)];
        int b = p / NN;
        rowb[e] = (b*NN + nb)*DD;
    }
}

__device__ __forceinline__ void stage_load(const __half* __restrict__ feats,
                                           const int* rowb, int blk,
                                           int tloc, int tid, uint4* A) {
    int kc = tid & 15;
#pragma unroll
    for (int it = 0; it < 4; ++it) {
        int row = it*16 + (tid >> 4);
        int e = tloc*64 + row;
        int p = (blk*TPB_TILES + tloc)*2 + (row >> 5);
        int ra = (kc < 8) ? (rowb[e] + kc*8) : (p*DD + (kc-8)*8);
        A[it] = *(const uint4*)(feats + ra);
    }
}

// stage_write: center row recovered from lane (kc^8)'s prefetch via shfl_xor.
__device__ __forceinline__ void stage_write(int tid, const uint4* A, __half* nf) {
    int kc = tid & 15;
#pragma unroll
    for (int it = 0; it < 4; ++it) {
        int row = it*16 + (tid >> 4);
        union { uint4 u; __half2 h[4]; } a, b, rr;
        a.u = A[it];
        b.u.x = (unsigned)__shfl_xor((int)a.u.x, 8);
        b.u.y = (unsigned)__shfl_xor((int)a.u.y, 8);
        b.u.z = (unsigned)__shfl_xor((int)a.u.z, 8);
        b.u.w = (unsigned)__shfl_xor((int)a.u.w, 8);
        if (kc < 8) {
#pragma unroll
            for (int j = 0; j < 4; ++j) rr.h[j] = __hsub2(a.h[j], b.h[j]);
        } else {
            rr.u = a.u;
        }
        int C = (row >> 4)*256 + kc*16 + ((row & 15) ^ kc);   // XOR swizzle
        *(uint4*)(nf + C*8) = rr.u;
    }
}

// ---------------- fused: mm1 + bn1relu + mm2 + stats2 + per-pair max/min ----------------
// LOCKED operating point (rounds 0-8 ledger): launch_bounds(256,4) +
// LDS>40KB (pad) -> 3 blocks/CU -> 170-reg budget -> resident weights,
// ZERO spill (r8: VGPR 112, FETCH 14.5 MB = ideal). mm2 operand-swapped.
__global__ void __launch_bounds__(256, 4)
k_fused_mfma(const __half* __restrict__ feats,
             const int* __restrict__ knn_idx,
             const __half* __restrict__ w1h,
             const __half* __restrict__ w2h,
             const float* __restrict__ ab1,
             float* __restrict__ gsum2,
             float* __restrict__ gsumsq2,
             float* __restrict__ wsmax,
             float* __restrict__ wsmin) {
    __shared__ __align__(16) __half nf[8192];     // 16 KB, swizzled chunks
    __shared__ __align__(16) __half y1s[8192];    // 16 KB, same swizzled layout
    __shared__ __align__(16) float abs_lds[256];  // bn1 a (0..127), c (128..255)
    __shared__ int rowb[TPB_TILES*64];            // 2 KB
    __shared__ float lds_pad[1312];               // 5.25 KB occupancy shaping
    int tid = threadIdx.x;
    int lane = tid & 63, wid = tid >> 6;
    int m = lane & 15, q = lane >> 4;

    fill_bases(knn_idx, blockIdx.x, tid, rowb);
    abs_lds[tid] = ab1[tid];
    ((volatile float*)lds_pad)[tid] = 0.f;

    half8 w1f[2][4], w2f[2][4];
#pragma unroll
    for (int ob = 0; ob < 2; ++ob)
#pragma unroll
        for (int t = 0; t < 4; ++t) {
            int o = wid*32 + ob*16 + m;
            w1f[ob][t] = *(const half8*)(w1h + o*CC + t*32 + q*8);
            w2f[ob][t] = *(const half8*)(w2h + o*CC + t*32 + q*8);
        }

    f32x4 zero4 = {0.f, 0.f, 0.f, 0.f};
    f32x4 ssum[2] = {zero4, zero4}, ssq[2] = {zero4, zero4};

    __syncthreads();
    uint4 pf[4];
    stage_load(feats, rowb, blockIdx.x, 0, tid, pf);

    for (int it = 0; it < TPB_TILES; ++it) {
        int tile = blockIdx.x * TPB_TILES + it;

        stage_write(tid, pf, nf);
        __syncthreads();                               // B1
        if (it + 1 < TPB_TILES) stage_load(feats, rowb, blockIdx.x, it + 1, tid, pf);

        f32x4 acc[2][4];
#pragma unroll
        for (int ob = 0; ob < 2; ++ob)
#pragma unroll
            for (int rbk = 0; rbk < 4; ++rbk) acc[ob][rbk] = zero4;

        // mm1: z1^T = w1 . nf^T
#pragma unroll
        for (int t = 0; t < 4; ++t) {
            int kct = t*4 + q;
            int sw = m ^ kct;
#pragma unroll
            for (int rbk = 0; rbk < 4; ++rbk) {
                half8 bfr = *(const half8*)(nf + (rbk*256 + kct*16 + sw)*8);
                acc[0][rbk] = __builtin_amdgcn_mfma_f32_16x16x32_f16(w1f[0][t], bfr, acc[0][rbk], 0, 0, 0);
                acc[1][rbk] = __builtin_amdgcn_mfma_f32_16x16x32_f16(w1f[1][t], bfr, acc[1][rbk], 0, 0, 0);
            }
        }

        // bn1 + relu, write y1 in swizzled chunk layout (a/c broadcast from LDS)
#pragma unroll
        for (int ob = 0; ob < 2; ++ob) {
            f32x4 av = *(const f32x4*)(abs_lds + wid*32 + ob*16 + q*4);
            f32x4 cv = *(const f32x4*)(abs_lds + 128 + wid*32 + ob*16 + q*4);
#pragma unroll
            for (int rbk = 0; rbk < 4; ++rbk) {
                f32x4 z = acc[ob][rbk];
                float y0 = relu_(fmaf(av[0], z[0], cv[0]));
                float y1 = relu_(fmaf(av[1], z[1], cv[1]));
                float y2 = relu_(fmaf(av[2], z[2], cv[2]));
                float y3 = relu_(fmaf(av[3], z[3], cv[3]));
                H2U p0, p1;
                p0.h = __floats2half2_rn(y0, y1);
                p1.h = __floats2half2_rn(y2, y3);
                int kcy = wid*4 + ob*2 + (q >> 1);
                int C = rbk*256 + kcy*16 + (m ^ kcy);
                uint2 v; v.x = p0.u; v.y = p1.u;
                *(uint2*)(y1s + C*8 + (q & 1)*4) = v;
            }
        }
        __syncthreads();                               // B2

        // mm2 SWAPPED: channel = lane&15, row = rbk*16 + q*4 + c
#pragma unroll
        for (int ob = 0; ob < 2; ++ob)
#pragma unroll
            for (int rbk = 0; rbk < 4; ++rbk) acc[ob][rbk] = zero4;
#pragma unroll
        for (int t = 0; t < 4; ++t) {
            int kct = t*4 + q;
            int sw = m ^ kct;
#pragma unroll
            for (int rbk = 0; rbk < 4; ++rbk) {
                half8 bfr = *(const half8*)(y1s + (rbk*256 + kct*16 + sw)*8);
                acc[0][rbk] = __builtin_amdgcn_mfma_f32_16x16x32_f16(bfr, w2f[0][t], acc[0][rbk], 0, 0, 0);
                acc[1][rbk] = __builtin_amdgcn_mfma_f32_16x16x32_f16(bfr, w2f[1][t], acc[1][rbk], 0, 0, 0);
            }
        }
        // stats2
#pragma unroll
        for (int ob = 0; ob < 2; ++ob)
#pragma unroll
            for (int rbk = 0; rbk < 4; ++rbk) {
                ssum[ob] += acc[ob][rbk];
                ssq[ob]  += acc[ob][rbk]*acc[ob][rbk];
            }
        // per-pair max/min: 7 in-thread fmax + 2 shfls
#pragma unroll
        for (int ob = 0; ob < 2; ++ob)
#pragma unroll
            for (int pr = 0; pr < 2; ++pr) {
                f32x4 x0 = acc[ob][pr*2], x1 = acc[ob][pr*2 + 1];
                float mx = fmaxf(fmaxf(fmaxf(x0[0], x0[1]), fmaxf(x0[2], x0[3])),
                                 fmaxf(fmaxf(x1[0], x1[1]), fmaxf(x1[2], x1[3])));
                float mn = fminf(fminf(fminf(x0[0], x0[1]), fminf(x0[2], x0[3])),
                                 fminf(fminf(x1[0], x1[1]), fminf(x1[2], x1[3])));
                mx = fmaxf(mx, __shfl_xor(mx, 16));
                mx = fmaxf(mx, __shfl_xor(mx, 32));
                mn = fminf(mn, __shfl_xor(mn, 16));
                mn = fminf(mn, __shfl_xor(mn, 32));
                if (lane < 16) {
                    int p = tile*2 + pr;
                    int o = wid*32 + ob*16 + m;
                    wsmax[(size_t)p*CC + o] = mx;
                    wsmin[(size_t)p*CC + o] = mn;
                }
            }
    }
#pragma unroll
    for (int ob = 0; ob < 2; ++ob) {
        float v  = ssum[ob][0] + ssum[ob][1] + ssum[ob][2] + ssum[ob][3];
        float v2 = ssq[ob][0]  + ssq[ob][1]  + ssq[ob][2]  + ssq[ob][3];
        v  += __shfl_xor(v, 16);  v  += __shfl_xor(v, 32);
        v2 += __shfl_xor(v2, 16); v2 += __shfl_xor(v2, 32);
        if (lane < 16) {
            int o = wid*32 + ob*16 + m;
            atomicAdd(&gsum2[o], v);
            atomicAdd(&gsumsq2[o], v2);
        }
    }
}

// ---------------- epilogue (absorbs finalize): bn2 params from gsum2/gsq2,
// bn2+relu on max/min, transpose to (B,C,N) ----------------
__global__ void __launch_bounds__(256) k_epilogue(const float* __restrict__ wsmax,
                                                  const float* __restrict__ wsmin,
                                                  const float* __restrict__ gsum2,
                                                  const float* __restrict__ gsq2,
                                                  const float* __restrict__ g2,
                                                  const float* __restrict__ b2,
                                                  float* __restrict__ out) {
    __shared__ float t[128*65];
    __shared__ float ab2s[256];
    int b = blockIdx.y;
    int n0 = blockIdx.x * 64;
    int tid = threadIdx.x;
    if (tid < 128) {
        int o = tid;
        float c = (float)ROWS;
        float mean = gsum2[o] / c;
        float var  = gsq2[o] / c - mean*mean;
        float a = g2[o] * rsqrtf(var + EPSV);
        ab2s[o] = a;
        ab2s[CC + o] = b2[o] - mean*a;
    }
    __syncthreads();
#pragma unroll
    for (int i = 0; i < 32; ++i) {
        int idx = i*256 + tid;
        int nl = idx >> 7, o = idx & 127;
        int n = n0 + nl;
        float v = 0.f;
        if (n < NN) {
            float a = ab2s[o], cc = ab2s[CC + o];
            size_t p = (size_t)b*NN + n;
            float z = (a >= 0.f) ? wsmax[p*CC + o] : wsmin[p*CC + o];
            v = fmaf(a, z, cc);
            v = v > 0.f ? v : 0.f;
        }
        t[o*65 + nl] = v;
    }
    __syncthreads();
#pragma unroll
    for (int i = 0; i < 32; ++i) {
        int idx = i*256 + tid;
        int o = idx >> 6, nl = idx & 63;
        int n = n0 + nl;
        if (n < NN) out[((size_t)b*CC + o)*NN + n] = t[o*65 + nl];
    }
}

extern "C" void kernel_launch(void* const* d_in, const int* in_sizes, int n_in,
                              void* d_out, int out_size, void* d_ws, size_t ws_size,
                              hipStream_t stream) {
    const float* x      = (const float*)d_in[0];
    const float* coords = (const float*)d_in[1];
    const float* w1     = (const float*)d_in[2];
    const float* g1     = (const float*)d_in[3];
    const float* b1     = (const float*)d_in[4];
    const float* w2     = (const float*)d_in[5];
    const float* g2     = (const float*)d_in[6];
    const float* b2     = (const float*)d_in[7];
    float* out = (float*)d_out;

    char* ws = (char*)d_ws;
    size_t off = 0;
    int* knn_idx = (int*)(ws + off);   off += (size_t)ROWS * sizeof(int);        // 3.32 MB
    float* stats = (float*)(ws + off); off += 1024 * sizeof(float);
    float* gsum2 = stats + 256, *gsq2 = stats + 384;
    float* ab1   = stats + 512;
    __half* feats = (__half*)(ws + off); off += (size_t)BB*NN*DD * sizeof(__half); // 3.32 MB
    __half* w1h   = (__half*)(ws + off); off += CC*CC * sizeof(__half);
    __half* w2h   = (__half*)(ws + off); off += CC*CC * sizeof(__half);
    float* wsmax = (float*)(ws + off);  off += (size_t)PAIRS*CC * sizeof(float);  // 13.3 MB
    float* wsmin = (float*)(ws + off);  off += (size_t)PAIRS*CC * sizeof(float);  // 13.3 MB
    int*   cnt   = (int*)(ws + off);    off += (size_t)PAIRS * sizeof(int);       // 104 KB
    float* Mfin  = (float*)(ws + off);  off += (size_t)MSTRIDE * sizeof(float);   // 50 KB
    // alias (dead before k_fused writes wsmin):
    float* Mpart = wsmin;                    // 256*12416 fp32 = 12.71 MB (<13.27)
    (void)ws_size; (void)in_sizes; (void)n_in; (void)out_size;

    dim3 gT((NN + 63)/64, BB);
    k_prep_feats<<<gT, 256, 0, stream>>>(x, feats, w1, w2, w1h, w2h, cnt, stats);
    k_knn<<<PAIRS/QPB, 256, 0, stream>>>(coords, knn_idx, cnt);
    k_gram<<<GRAM_BLOCKS, 256, 0, stream>>>(feats, knn_idx, cnt, Mpart);
    k_gram_reduce<<<(MSTRIDE + 255)/256, 256, 0, stream>>>(Mpart, Mfin);
    k_stats1<<<CC, 256, 0, stream>>>(Mfin, w1h, g1, b1, ab1);
    k_fused_mfma<<<GRID_MM, 256, 0, stream>>>(feats, knn_idx, w1h, w2h, ab1,
                                              gsum2, gsq2, wsmax, wsmin);
    dim3 gE((NN + 63)/64, BB);
    k_epilogue<<<gE, 256, 0, stream>>>(wsmax, wsmin, gsum2, gsq2, g2, b2, out);
}

// Round 11
// 360.930 us; speedup vs baseline: 1.0443x; 1.0443x over previous
//
#include <hip/hip_runtime.h>
#include <hip/hip_fp16.h>
#include <stdint.h>

#define BB 16
#define NN 1620
#define DD 64
#define CC 128
#define KK 32
#define EPSV 1e-5f
#define PAIRS (BB*NN)            // 25920
#define ROWS  (PAIRS*KK)         // 829440
#define TILES (PAIRS/2)          // 12960 tiles of 64 rows
#define TPB_TILES 8
#define GRID_MM (TILES/TPB_TILES) // 1620
#define NCHUNK 26                // ceil(1620/64)
#define GRAM_BLOCKS 256
#define MSTRIDE 12416            // 3*4096 mats + 64 vcf + 64 vf
#define QPB 4                    // knn queries per 256-thread block
#define HSTRIDE 264              // replica stride (ints): 264 % 32 == 8 ->
                                 // replicas of a bin land in 4 DISTINCT banks

typedef _Float16 half8 __attribute__((ext_vector_type(8)));
typedef float f32x4 __attribute__((ext_vector_type(4)));

__device__ __forceinline__ float relu_(float v){ return v > 0.f ? v : 0.f; }

union H2U { __half2 h; unsigned u; };

// ---------------- fused prologue: transpose x -> feats fp16, convert w,
// zero cnt/stats (absorbs k_convert_w + both memsets; 416 blocks x 256) ----
__global__ void __launch_bounds__(256) k_prep_feats(const float* __restrict__ x,
                                                    __half* __restrict__ feats,
                                                    const float* __restrict__ w1,
                                                    const float* __restrict__ w2,
                                                    __half* __restrict__ w1h,
                                                    __half* __restrict__ w2h,
                                                    int* __restrict__ cnt,
                                                    float* __restrict__ stats) {
    __shared__ float t[64*65];
    int b = blockIdx.y;
    int n0 = blockIdx.x * 64;
    int tid = threadIdx.x;

    // distributed side-work: w convert (16384) + cnt zero (25920) + stats zero (512)
    {
        int gid = (blockIdx.y * gridDim.x + blockIdx.x)*256 + tid;
        if (gid < CC*CC) {
            w1h[gid] = __float2half(w1[gid]);
            w2h[gid] = __float2half(w2[gid]);
        }
        int zid = gid - CC*CC;
        if (zid >= 0 && zid < PAIRS) cnt[zid] = 0;
        int sid = zid - PAIRS;
        if (sid >= 0 && sid < 512) stats[sid] = 0.f;
    }

#pragma unroll
    for (int i = 0; i < 16; ++i) {
        int idx = i*256 + tid;
        int d = idx >> 6, nl = idx & 63;
        int n = n0 + nl;
        float v = 0.f;
        if (n < NN) v = x[((size_t)b*DD + d)*NN + n];
        t[d*65 + nl] = v;
    }
    __syncthreads();
#pragma unroll
    for (int i = 0; i < 8; ++i) {
        int idx = i*256 + tid;            // 64 nl x 32 d-pairs
        int nl = idx >> 5, dp = idx & 31;
        int n = n0 + nl;
        if (n < NN) {
            __half2 h = __floats2half2_rn(t[(dp*2)*65 + nl], t[(dp*2+1)*65 + nl]);
            *(__half2*)(feats + ((size_t)b*NN + n)*DD + dp*2) = h;
        }
    }
}

// ---------------- KNN: radix-histogram rank selection ----------------
// Round-10 lever: coords (float4 AoS incl. precomputed |c|^2, 25.9 KB) and
// the histograms (16.9 KB) TIME-SHARE one LDS region -- coords are dead
// once keys are in registers. 26 KB/block -> 6 blocks/CU = 24 waves (was
// 36.9 KB -> 4 blocks, 39% occupancy). Distance loop: 1 ds_read_b128/point
// (was 3 ds_read_b32) and |c|^2 computed once per block (was per wave).
// Numerics bit-identical: same expressions, fp contract(off).
__global__ void __launch_bounds__(256) k_knn(const float* __restrict__ coords,
                                             int* __restrict__ idx_out,
                                             int* __restrict__ cnt) {
#pragma clang fp contract(off)
    __shared__ __align__(16) char smem[NN*16];   // 25.9 KB: coords THEN hists
    __shared__ unsigned bcast[QPB][2];
    float4* cxyz = (float4*)smem;
    int tid = threadIdx.x;
    int w = tid >> 6, lane = tid & 63;
    int p = blockIdx.x*QPB + w;
    int b = (blockIdx.x*QPB) / NN;        // block-uniform (NN % QPB == 0)
    int n = p - b*NN;
    const float* cb = coords + (size_t)b*NN*3;

    // stage coords + per-point |c|^2
    for (int i = tid; i < NN; i += 256) {
        float cx = cb[i*3+0], cy = cb[i*3+1], cz = cb[i*3+2];
        float4 c; c.x = cx; c.y = cy; c.z = cz;
        c.w = (cx*cx + cy*cy) + cz*cz;
        cxyz[i] = c;
    }
    __syncthreads();

    float4 qc = cxyz[n];
    float qx = qc.x, qy = qc.y, qz = qc.z, sqn = qc.w;

    unsigned key[NCHUNK];
#pragma unroll
    for (int i = 0; i < NCHUNK; ++i) {
        int m = lane + i*64;
        unsigned u = 0xFFFFFFFFu;
        if (m < NN) {
            float4 c = cxyz[m];
            float dot = (qx*c.x + qy*c.y) + qz*c.z;
            float d = (sqn + c.w) - 2.0f*dot;
            unsigned t = __float_as_uint(d);
            u = (t & 0x80000000u) ? ~t : (t | 0x80000000u);
        }
        key[i] = u;
    }
    __syncthreads();           // ALL waves done reading coords -> reuse LDS

    int* histw = (int*)smem + w*(4*HSTRIDE);
    int* hrep  = histw + (lane & 3)*HSTRIDE;

    // ---- pass A: histogram on key[31:24] ----
    for (int i = lane; i < 4*HSTRIDE; i += 64) histw[i] = 0;
    __syncthreads();
#pragma unroll
    for (int i = 0; i < NCHUNK; ++i) {
        int m = lane + i*64;
        if (m < NN) atomicAdd(&hrep[key[i] >> 24], 1);
    }
    __syncthreads();
    {
        int v0 = 0, v1 = 0, v2 = 0, v3 = 0;
#pragma unroll
        for (int c = 0; c < 4; ++c) {
            const int* h = histw + c*HSTRIDE;
            v0 += h[lane*4+0]; v1 += h[lane*4+1];
            v2 += h[lane*4+2]; v3 += h[lane*4+3];
        }
        int c1 = v0+v1, c2 = c1+v2, c3 = c2+v3;
        int inc = c3;
#pragma unroll
        for (int off = 1; off < 64; off <<= 1) {
            int t = __shfl_up(inc, off);
            if (lane >= off) inc += t;
        }
        int base = inc - c3;
        if (base < KK) {
            int u0 = base+v0, u1 = base+c1, u2 = base+c2, u3 = base+c3;
            if      (u0 >= KK) { bcast[w][0] = lane*4+0; bcast[w][1] = base; }
            else if (u1 >= KK) { bcast[w][0] = lane*4+1; bcast[w][1] = u0; }
            else if (u2 >= KK) { bcast[w][0] = lane*4+2; bcast[w][1] = u1; }
            else if (u3 >= KK) { bcast[w][0] = lane*4+3; bcast[w][1] = u2; }
        }
    }
    __syncthreads();
    unsigned BA = bcast[w][0];
    int rA = KK - (int)bcast[w][1];
    __syncthreads();

    // ---- pass B: histogram on key[23:16] within bucket BA ----
    for (int i = lane; i < 4*HSTRIDE; i += 64) histw[i] = 0;
    __syncthreads();
#pragma unroll
    for (int i = 0; i < NCHUNK; ++i) {
        int m = lane + i*64;
        if (m < NN && (key[i] >> 24) == BA) atomicAdd(&hrep[(key[i] >> 16) & 255], 1);
    }
    __syncthreads();
    {
        int v0 = 0, v1 = 0, v2 = 0, v3 = 0;
#pragma unroll
        for (int c = 0; c < 4; ++c) {
            const int* h = histw + c*HSTRIDE;
            v0 += h[lane*4+0]; v1 += h[lane*4+1];
            v2 += h[lane*4+2]; v3 += h[lane*4+3];
        }
        int c1 = v0+v1, c2 = c1+v2, c3 = c2+v3;
        int inc = c3;
#pragma unroll
        for (int off = 1; off < 64; off <<= 1) {
            int t = __shfl_up(inc, off);
            if (lane >= off) inc += t;
        }
        int base = inc - c3;
        if (base < rA) {
            int u0 = base+v0, u1 = base+c1, u2 = base+c2, u3 = base+c3;
            if      (u0 >= rA) { bcast[w][0] = lane*4+0; bcast[w][1] = base; }
            else if (u1 >= rA) { bcast[w][0] = lane*4+1; bcast[w][1] = u0; }
            else if (u2 >= rA) { bcast[w][0] = lane*4+2; bcast[w][1] = u1; }
            else if (u3 >= rA) { bcast[w][0] = lane*4+3; bcast[w][1] = u2; }
        }
    }
    __syncthreads();
    unsigned prefix16 = (BA << 8) | bcast[w][0];
    int r = rA - (int)bcast[w][1];

    // ---- extract exact 32nd (key, m) pair (wave-local, no barriers) ----
    unsigned long long fl = 0;
    for (int round = 0; round < r; ++round) {
        unsigned long long best = ~0ull;
#pragma unroll
        for (int i = 0; i < NCHUNK; ++i) {
            if ((key[i] >> 16) == prefix16) {
                unsigned long long v = ((unsigned long long)key[i] << 32) | (unsigned)(lane + i*64);
                if (v > fl && v < best) best = v;
            }
        }
#pragma unroll
        for (int off = 32; off; off >>= 1) {
            unsigned long long o = __shfl_xor(best, off, 64);
            if (o < best) best = o;
        }
        fl = best;
    }
    unsigned kstar = (unsigned)(fl >> 32);
    unsigned mstar = (unsigned)fl;

    int cnt_ = 0;
    unsigned long long mylow = (1ull << lane) - 1ull;
#pragma unroll
    for (int i = 0; i < NCHUNK; ++i) {
        unsigned m = lane + i*64;
        bool sel = (key[i] < kstar) || (key[i] == kstar && m <= mstar);
        unsigned long long bal = __ballot(sel);
        if (sel) {
            int pos = cnt_ + __popcll(bal & mylow);
            idx_out[p*KK + pos] = (int)m;
            atomicAdd(&cnt[b*NN + (int)m], 1);
        }
        cnt_ += __popcll(bal);
    }
}

// ---------------- gather-sum: s_p = sum_k f_nb(p,k), fp32 ----------------
// (reinstated: round-10 inline-in-gram version put the 32-iter gather on
// gram's barrier-bounded critical path with 256 blocks; separate kernel
// hides it across 6480 blocks)
__global__ void __launch_bounds__(256) k_gather_sum(const __half* __restrict__ feats,
                                                    const int* __restrict__ knn_idx,
                                                    float* __restrict__ s_arr) {
    int w = threadIdx.x >> 6, lane = threadIdx.x & 63;
    int p = blockIdx.x*4 + w;
    int b = p / NN;
    int bbase = b*NN;
    int idx = 0;
    if (lane < KK) idx = knn_idx[p*KK + lane];
    float s = 0.f;
#pragma unroll
    for (int k = 0; k < KK; ++k) {
        int nb = __shfl(idx, k);
        s += __half2float(feats[((size_t)(bbase + nb))*DD + lane]);
    }
    s_arr[(size_t)p*DD + lane] = s;
}

// ---------------- gram: per-block partial M1/M2/M3 + vectors ----------------
__global__ void __launch_bounds__(256) k_gram(const __half* __restrict__ feats,
                                              const float* __restrict__ s_arr,
                                              const int* __restrict__ cnt,
                                              float* __restrict__ Mpart) {
    __shared__ float fs[4][64];
    __shared__ float ss[4][64];
    __shared__ float cs[4];
    int tid = threadIdx.x;
    int rt = tid >> 4, ct = tid & 15;
    int r0 = rt*4, c0 = ct*4;
    float m1a[4][4] = {{0}}, m2a[4][4] = {{0}}, m3a[4][4] = {{0}};
    float vcf4[4] = {0,0,0,0}, vf4[4] = {0,0,0,0};

    int per = (PAIRS + GRAM_BLOCKS - 1)/GRAM_BLOCKS;   // 102
    int p0 = blockIdx.x * per;
    int p1 = p0 + per; if (p1 > PAIRS) p1 = PAIRS;

    for (int pc = p0; pc < p1; pc += 4) {
        __syncthreads();
        int sub = tid >> 6, l = tid & 63;
        int pp = pc + sub;
        if (pp < p1) {
            fs[sub][l] = __half2float(feats[(size_t)pp*DD + l]);
            ss[sub][l] = s_arr[(size_t)pp*DD + l];
            if (l == 0) cs[sub] = (float)cnt[pp];
        }
        __syncthreads();
        int e = p1 - pc; if (e > 4) e = 4;
        for (int j = 0; j < e; ++j) {
            float cn = cs[j];
            float fr[4], sr[4], fc[4];
#pragma unroll
            for (int a = 0; a < 4; ++a) { fr[a] = fs[j][r0+a]; sr[a] = ss[j][r0+a]; fc[a] = fs[j][c0+a]; }
#pragma unroll
            for (int a = 0; a < 4; ++a) {
                float cfr = cn * fr[a];
#pragma unroll
                for (int bc = 0; bc < 4; ++bc) {
                    m1a[a][bc] = fmaf(cfr,   fc[bc], m1a[a][bc]);
                    m2a[a][bc] = fmaf(sr[a], fc[bc], m2a[a][bc]);
                    m3a[a][bc] = fmaf(fr[a], fc[bc], m3a[a][bc]);
                }
                if (ct == 0) { vcf4[a] += cfr; vf4[a] += fr[a]; }
            }
        }
    }
    float* out = Mpart + (size_t)blockIdx.x * MSTRIDE;
#pragma unroll
    for (int a = 0; a < 4; ++a)
#pragma unroll
        for (int bc = 0; bc < 4; ++bc) {
            int idx = (r0+a)*64 + c0+bc;
            out[idx]        = m1a[a][bc];
            out[4096 + idx] = m2a[a][bc];
            out[8192 + idx] = m3a[a][bc];
        }
    if (ct == 0)
#pragma unroll
        for (int a = 0; a < 4; ++a) {
            out[12288 + r0+a] = vcf4[a];
            out[12352 + r0+a] = vf4[a];
        }
}

__global__ void __launch_bounds__(256) k_gram_reduce(const float* __restrict__ Mpart,
                                                     float* __restrict__ Mfin) {
    int e = blockIdx.x*256 + threadIdx.x;
    if (e < MSTRIDE) {
        float s = 0.f;
        for (int p = 0; p < GRAM_BLOCKS; ++p) s += Mpart[(size_t)p*MSTRIDE + e];
        Mfin[e] = s;
    }
}

// ---------------- stats1 from Gram: one block per output channel o ----------------
__global__ void __launch_bounds__(256) k_stats1(const float* __restrict__ M,
                                                const __half* __restrict__ w1h,
                                                const float* __restrict__ g1,
                                                const float* __restrict__ b1,
                                                float* __restrict__ ab1) {
    __shared__ float wl[64], wr[64];
    __shared__ float redA[256], redB[256];
    int o = blockIdx.x, tid = threadIdx.x;
    if (tid < 64)       wl[tid]    = __half2float(w1h[o*CC + tid]);
    else if (tid < 128) wr[tid-64] = __half2float(w1h[o*CC + tid]);
    __syncthreads();
    const float* M1 = M;
    const float* M2 = M + 4096;
    const float* M3 = M + 8192;
    const float* vcf = M + 12288;
    const float* vf  = M + 12352;
    float part = 0.f;
    for (int e = tid; e < 4096; e += 256) {
        int i = e >> 6, j = e & 63;
        float m1 = M1[e], m2 = M2[e], m2t = M2[j*64 + i], m3 = M3[e];
        float A  = m1 - m2 - m2t + 32.f*m3;   // sum u u^T
        float Bc = m2 - 32.f*m3;              // sum u v^T
        part += wl[i]*(A*wl[j] + 2.f*Bc*wr[j]) + 32.f*wr[i]*m3*wr[j];
    }
    float psum = 0.f;
    if (tid < 64) psum = wl[tid]*(vcf[tid] - 32.f*vf[tid]) + 32.f*wr[tid]*vf[tid];
    redA[tid] = part; redB[tid] = psum;
    __syncthreads();
    for (int s = 128; s > 0; s >>= 1) {
        if (tid < s) { redA[tid] += redA[tid+s]; redB[tid] += redB[tid+s]; }
        __syncthreads();
    }
    if (tid == 0) {
        float sumsq = redA[0], sum = redB[0];
        float mean = sum / (float)ROWS;
        float var  = sumsq / (float)ROWS - mean*mean;
        float a = g1[o] * rsqrtf(var + EPSV);
        ab1[o] = a;
        ab1[CC + o] = b1[o] - mean*a;
    }
}

// ============ staging helpers: coalesced gather + XOR-swizzled LDS ============
__device__ __forceinline__ void fill_bases(const int* __restrict__ knn_idx,
                                           int blk, int tid, int* rowb) {
#pragma unroll
    for (int e = tid; e < TPB_TILES*64; e += 256) {
        int tile = blk*TPB_TILES + (e >> 6);
        int rr = e & 63;
        int p = tile*2 + (rr >> 5);
        int nb = knn_idx[p*KK + (rr & 31)];
        int b = p / NN;
        rowb[e] = (b*NN + nb)*DD;
    }
}

__device__ __forceinline__ void stage_load(const __half* __restrict__ feats,
                                           const int* rowb, int blk,
                                           int tloc, int tid, uint4* A) {
    int kc = tid & 15;
#pragma unroll
    for (int it = 0; it < 4; ++it) {
        int row = it*16 + (tid >> 4);
        int e = tloc*64 + row;
        int p = (blk*TPB_TILES + tloc)*2 + (row >> 5);
        int ra = (kc < 8) ? (rowb[e] + kc*8) : (p*DD + (kc-8)*8);
        A[it] = *(const uint4*)(feats + ra);
    }
}

// stage_write: center row recovered from lane (kc^8)'s prefetch via shfl_xor.
__device__ __forceinline__ void stage_write(int tid, const uint4* A, __half* nf) {
    int kc = tid & 15;
#pragma unroll
    for (int it = 0; it < 4; ++it) {
        int row = it*16 + (tid >> 4);
        union { uint4 u; __half2 h[4]; } a, b, rr;
        a.u = A[it];
        b.u.x = (unsigned)__shfl_xor((int)a.u.x, 8);
        b.u.y = (unsigned)__shfl_xor((int)a.u.y, 8);
        b.u.z = (unsigned)__shfl_xor((int)a.u.z, 8);
        b.u.w = (unsigned)__shfl_xor((int)a.u.w, 8);
        if (kc < 8) {
#pragma unroll
            for (int j = 0; j < 4; ++j) rr.h[j] = __hsub2(a.h[j], b.h[j]);
        } else {
            rr.u = a.u;
        }
        int C = (row >> 4)*256 + kc*16 + ((row & 15) ^ kc);   // XOR swizzle
        *(uint4*)(nf + C*8) = rr.u;
    }
}

// ---------------- fused: mm1 + bn1relu + mm2 + stats2 + per-pair max/min ----------------
// LOCKED operating point (rounds 0-8 ledger): launch_bounds(256,4) +
// LDS>40KB (pad) -> 3 blocks/CU -> 170-reg budget -> resident weights,
// ZERO spill (r8: VGPR 112, FETCH 14.5 MB = ideal). mm2 operand-swapped.
__global__ void __launch_bounds__(256, 4)
k_fused_mfma(const __half* __restrict__ feats,
             const int* __restrict__ knn_idx,
             const __half* __restrict__ w1h,
             const __half* __restrict__ w2h,
             const float* __restrict__ ab1,
             float* __restrict__ gsum2,
             float* __restrict__ gsumsq2,
             float* __restrict__ wsmax,
             float* __restrict__ wsmin) {
    __shared__ __align__(16) __half nf[8192];     // 16 KB, swizzled chunks
    __shared__ __align__(16) __half y1s[8192];    // 16 KB, same swizzled layout
    __shared__ __align__(16) float abs_lds[256];  // bn1 a (0..127), c (128..255)
    __shared__ int rowb[TPB_TILES*64];            // 2 KB
    __shared__ float lds_pad[1312];               // 5.25 KB occupancy shaping
    int tid = threadIdx.x;
    int lane = tid & 63, wid = tid >> 6;
    int m = lane & 15, q = lane >> 4;

    fill_bases(knn_idx, blockIdx.x, tid, rowb);
    abs_lds[tid] = ab1[tid];
    ((volatile float*)lds_pad)[tid] = 0.f;

    half8 w1f[2][4], w2f[2][4];
#pragma unroll
    for (int ob = 0; ob < 2; ++ob)
#pragma unroll
        for (int t = 0; t < 4; ++t) {
            int o = wid*32 + ob*16 + m;
            w1f[ob][t] = *(const half8*)(w1h + o*CC + t*32 + q*8);
            w2f[ob][t] = *(const half8*)(w2h + o*CC + t*32 + q*8);
        }

    f32x4 zero4 = {0.f, 0.f, 0.f, 0.f};
    f32x4 ssum[2] = {zero4, zero4}, ssq[2] = {zero4, zero4};

    __syncthreads();
    uint4 pf[4];
    stage_load(feats, rowb, blockIdx.x, 0, tid, pf);

    for (int it = 0; it < TPB_TILES; ++it) {
        int tile = blockIdx.x * TPB_TILES + it;

        stage_write(tid, pf, nf);
        __syncthreads();                               // B1
        if (it + 1 < TPB_TILES) stage_load(feats, rowb, blockIdx.x, it + 1, tid, pf);

        f32x4 acc[2][4];
#pragma unroll
        for (int ob = 0; ob < 2; ++ob)
#pragma unroll
            for (int rbk = 0; rbk < 4; ++rbk) acc[ob][rbk] = zero4;

        // mm1: z1^T = w1 . nf^T
#pragma unroll
        for (int t = 0; t < 4; ++t) {
            int kct = t*4 + q;
            int sw = m ^ kct;
#pragma unroll
            for (int rbk = 0; rbk < 4; ++rbk) {
                half8 bfr = *(const half8*)(nf + (rbk*256 + kct*16 + sw)*8);
                acc[0][rbk] = __builtin_amdgcn_mfma_f32_16x16x32_f16(w1f[0][t], bfr, acc[0][rbk], 0, 0, 0);
                acc[1][rbk] = __builtin_amdgcn_mfma_f32_16x16x32_f16(w1f[1][t], bfr, acc[1][rbk], 0, 0, 0);
            }
        }

        // bn1 + relu, write y1 in swizzled chunk layout (a/c broadcast from LDS)
#pragma unroll
        for (int ob = 0; ob < 2; ++ob) {
            f32x4 av = *(const f32x4*)(abs_lds + wid*32 + ob*16 + q*4);
            f32x4 cv = *(const f32x4*)(abs_lds + 128 + wid*32 + ob*16 + q*4);
#pragma unroll
            for (int rbk = 0; rbk < 4; ++rbk) {
                f32x4 z = acc[ob][rbk];
                float y0 = relu_(fmaf(av[0], z[0], cv[0]));
                float y1 = relu_(fmaf(av[1], z[1], cv[1]));
                float y2 = relu_(fmaf(av[2], z[2], cv[2]));
                float y3 = relu_(fmaf(av[3], z[3], cv[3]));
                H2U p0, p1;
                p0.h = __floats2half2_rn(y0, y1);
                p1.h = __floats2half2_rn(y2, y3);
                int kcy = wid*4 + ob*2 + (q >> 1);
                int C = rbk*256 + kcy*16 + (m ^ kcy);
                uint2 v; v.x = p0.u; v.y = p1.u;
                *(uint2*)(y1s + C*8 + (q & 1)*4) = v;
            }
        }
        __syncthreads();                               // B2

        // mm2 SWAPPED: channel = lane&15, row = rbk*16 + q*4 + c
#pragma unroll
        for (int ob = 0; ob < 2; ++ob)
#pragma unroll
            for (int rbk = 0; rbk < 4; ++rbk) acc[ob][rbk] = zero4;
#pragma unroll
        for (int t = 0; t < 4; ++t) {
            int kct = t*4 + q;
            int sw = m ^ kct;
#pragma unroll
            for (int rbk = 0; rbk < 4; ++rbk) {
                half8 bfr = *(const half8*)(y1s + (rbk*256 + kct*16 + sw)*8);
                acc[0][rbk] = __builtin_amdgcn_mfma_f32_16x16x32_f16(bfr, w2f[0][t], acc[0][rbk], 0, 0, 0);
                acc[1][rbk] = __builtin_amdgcn_mfma_f32_16x16x32_f16(bfr, w2f[1][t], acc[1][rbk], 0, 0, 0);
            }
        }
        // stats2
#pragma unroll
        for (int ob = 0; ob < 2; ++ob)
#pragma unroll
            for (int rbk = 0; rbk < 4; ++rbk) {
                ssum[ob] += acc[ob][rbk];
                ssq[ob]  += acc[ob][rbk]*acc[ob][rbk];
            }
        // per-pair max/min: 7 in-thread fmax + 2 shfls
#pragma unroll
        for (int ob = 0; ob < 2; ++ob)
#pragma unroll
            for (int pr = 0; pr < 2; ++pr) {
                f32x4 x0 = acc[ob][pr*2], x1 = acc[ob][pr*2 + 1];
                float mx = fmaxf(fmaxf(fmaxf(x0[0], x0[1]), fmaxf(x0[2], x0[3])),
                                 fmaxf(fmaxf(x1[0], x1[1]), fmaxf(x1[2], x1[3])));
                float mn = fminf(fminf(fminf(x0[0], x0[1]), fminf(x0[2], x0[3])),
                                 fminf(fminf(x1[0], x1[1]), fminf(x1[2], x1[3])));
                mx = fmaxf(mx, __shfl_xor(mx, 16));
                mx = fmaxf(mx, __shfl_xor(mx, 32));
                mn = fminf(mn, __shfl_xor(mn, 16));
                mn = fminf(mn, __shfl_xor(mn, 32));
                if (lane < 16) {
                    int p = tile*2 + pr;
                    int o = wid*32 + ob*16 + m;
                    wsmax[(size_t)p*CC + o] = mx;
                    wsmin[(size_t)p*CC + o] = mn;
                }
            }
    }
#pragma unroll
    for (int ob = 0; ob < 2; ++ob) {
        float v  = ssum[ob][0] + ssum[ob][1] + ssum[ob][2] + ssum[ob][3];
        float v2 = ssq[ob][0]  + ssq[ob][1]  + ssq[ob][2]  + ssq[ob][3];
        v  += __shfl_xor(v, 16);  v  += __shfl_xor(v, 32);
        v2 += __shfl_xor(v2, 16); v2 += __shfl_xor(v2, 32);
        if (lane < 16) {
            int o = wid*32 + ob*16 + m;
            atomicAdd(&gsum2[o], v);
            atomicAdd(&gsumsq2[o], v2);
        }
    }
}

// ---------------- epilogue (absorbs finalize): bn2 params from gsum2/gsq2,
// bn2+relu on max/min, transpose to (B,C,N) ----------------
__global__ void __launch_bounds__(256) k_epilogue(const float* __restrict__ wsmax,
                                                  const float* __restrict__ wsmin,
                                                  const float* __restrict__ gsum2,
                                                  const float* __restrict__ gsq2,
                                                  const float* __restrict__ g2,
                                                  const float* __restrict__ b2,
                                                  float* __restrict__ out) {
    __shared__ float t[128*65];
    __shared__ float ab2s[256];
    int b = blockIdx.y;
    int n0 = blockIdx.x * 64;
    int tid = threadIdx.x;
    if (tid < 128) {
        int o = tid;
        float c = (float)ROWS;
        float mean = gsum2[o] / c;
        float var  = gsq2[o] / c - mean*mean;
        float a = g2[o] * rsqrtf(var + EPSV);
        ab2s[o] = a;
        ab2s[CC + o] = b2[o] - mean*a;
    }
    __syncthreads();
#pragma unroll
    for (int i = 0; i < 32; ++i) {
        int idx = i*256 + tid;
        int nl = idx >> 7, o = idx & 127;
        int n = n0 + nl;
        float v = 0.f;
        if (n < NN) {
            float a = ab2s[o], cc = ab2s[CC + o];
            size_t p = (size_t)b*NN + n;
            float z = (a >= 0.f) ? wsmax[p*CC + o] : wsmin[p*CC + o];
            v = fmaf(a, z, cc);
            v = v > 0.f ? v : 0.f;
        }
        t[o*65 + nl] = v;
    }
    __syncthreads();
#pragma unroll
    for (int i = 0; i < 32; ++i) {
        int idx = i*256 + tid;
        int o = idx >> 6, nl = idx & 63;
        int n = n0 + nl;
        if (n < NN) out[((size_t)b*CC + o)*NN + n] = t[o*65 + nl];
    }
}

extern "C" void kernel_launch(void* const* d_in, const int* in_sizes, int n_in,
                              void* d_out, int out_size, void* d_ws, size_t ws_size,
                              hipStream_t stream) {
    const float* x      = (const float*)d_in[0];
    const float* coords = (const float*)d_in[1];
    const float* w1     = (const float*)d_in[2];
    const float* g1     = (const float*)d_in[3];
    const float* b1     = (const float*)d_in[4];
    const float* w2     = (const float*)d_in[5];
    const float* g2     = (const float*)d_in[6];
    const float* b2     = (const float*)d_in[7];
    float* out = (float*)d_out;

    char* ws = (char*)d_ws;
    size_t off = 0;
    int* knn_idx = (int*)(ws + off);   off += (size_t)ROWS * sizeof(int);        // 3.32 MB
    float* stats = (float*)(ws + off); off += 1024 * sizeof(float);
    float* gsum2 = stats + 256, *gsq2 = stats + 384;
    float* ab1   = stats + 512;
    __half* feats = (__half*)(ws + off); off += (size_t)BB*NN*DD * sizeof(__half); // 3.32 MB
    __half* w1h   = (__half*)(ws + off); off += CC*CC * sizeof(__half);
    __half* w2h   = (__half*)(ws + off); off += CC*CC * sizeof(__half);
    float* wsmax = (float*)(ws + off);  off += (size_t)PAIRS*CC * sizeof(float);  // 13.3 MB
    float* wsmin = (float*)(ws + off);  off += (size_t)PAIRS*CC * sizeof(float);  // 13.3 MB
    int*   cnt   = (int*)(ws + off);    off += (size_t)PAIRS * sizeof(int);       // 104 KB
    float* Mfin  = (float*)(ws + off);  off += (size_t)MSTRIDE * sizeof(float);   // 50 KB
    // aliases (dead before k_fused writes wsmax/wsmin):
    float* s_arr = wsmax;                    // PAIRS*64 fp32 = 6.64 MB  (<13.3)
    float* Mpart = wsmin;                    // 256*12416 fp32 = 12.71 MB (<13.27)
    (void)ws_size; (void)in_sizes; (void)n_in; (void)out_size;

    dim3 gT((NN + 63)/64, BB);
    k_prep_feats<<<gT, 256, 0, stream>>>(x, feats, w1, w2, w1h, w2h, cnt, stats);
    k_knn<<<PAIRS/QPB, 256, 0, stream>>>(coords, knn_idx, cnt);
    k_gather_sum<<<PAIRS/4, 256, 0, stream>>>(feats, knn_idx, s_arr);
    k_gram<<<GRAM_BLOCKS, 256, 0, stream>>>(feats, s_arr, cnt, Mpart);
    k_gram_reduce<<<(MSTRIDE + 255)/256, 256, 0, stream>>>(Mpart, Mfin);
    k_stats1<<<CC, 256, 0, stream>>>(Mfin, w1h, g1, b1, ab1);
    k_fused_mfma<<<GRID_MM, 256, 0, stream>>>(feats, knn_idx, w1h, w2h, ab1,
                                              gsum2, gsq2, wsmax, wsmin);
    dim3 gE((NN + 63)/64, BB);
    k_epilogue<<<gE, 256, 0, stream>>>(wsmax, wsmin, gsum2, gsq2, g2, b2, out);
}